// Round 3
// baseline (1078.062 us; speedup 1.0000x reference)
//
#include <hip/hip_runtime.h>
#include <cstddef>
#include <cstdint>

typedef float f2    __attribute__((ext_vector_type(2)));
typedef float f32x4 __attribute__((ext_vector_type(4)));
typedef short bf16x8 __attribute__((ext_vector_type(8)));

__device__ __forceinline__ float fast_exp2(float x) { return __builtin_amdgcn_exp2f(x); }
__device__ __forceinline__ float fast_log2(float x) { return __builtin_amdgcn_logf(x); }

__device__ __forceinline__ short bf16rne(float x) {
  uint32_t u = __float_as_uint(x);
  u += 0x7fffu + ((u >> 16) & 1u);
  return (short)(u >> 16);
}

// LDS-only barrier: no vmcnt drain, global prefetch stays in flight.
__device__ __forceinline__ void bar_lds() {
  asm volatile("s_waitcnt lgkmcnt(0)\n\ts_barrier" ::: "memory");
}

namespace {
constexpr int Bc = 256, Tc = 1024, Kc = 128;
constexpr int ROWS = 16;
constexpr int NC = 96;          // time chunks -> 1536 blocks = 6 per CU
constexpr int WARM = 12;        // warmup; kappa<=0.29/step -> dir err ~5e-7 << bf16 noise
constexpr int MEAS = 1023 - WARM;  // 1011 measured steps, split via s_c = floor(1011*c/96)
constexpr float L2E = 1.4426950408889634f;
constexpr float LN2 = 0.6931471805599453f;
constexpr int PSTR = 136;
// Workspace: contrib[NC][Bc] floats = 96 KB.
}

// Chunked-telescope CRF forward (R2 engine, occupancy-tuned geometry).
// R2 diagnosis: chunk kernel ~64us (inferred: dur_us minus the stable ~138us
// harness overhead) with all per-CU throughput floors (VALU ~10us, HBM 21us,
// L3-served re-reads) far away -> still latency-hole dominated at 3 blocks/CU.
// Fix: NC=96 -> 1536 blocks = 6/CU (VGPR 76 allows 6 waves/SIMD), and WARM
// 15 -> 12 (Birkhoff kappa<=0.29 => boundary dir err ~5e-7, vs bf16 noise
// ~1e-3 that already passes with absmax 0.0). WARM=12 = 3 exact quads, so
// phase 2 resumes at ring phase u=0 with standard quads (all u static).
// Chunk c: warm-start (ones) at s_c = floor(1011c/96), 12 warmup steps,
// Amid at s_c+12, then L_c = s_{c+1}-s_c in {10,11} measured steps, Aend at
// s_c+12+L_c = s_{c+1}+12 (= chunk c+1's Amid point; telescopes). Chunk 0
// starts exact (2^((start+e_0)L2E)) so its whole range is measured; last
// chunk (c=95) ends at 1000+12+11 = 1023 and end-weights with 2^(end*L2E).
// logZ = LN2 * [Aend^(0) + sum_{c>=1}(Aend^(c)-Amid^(c))].
// Step engine unchanged: 16 batch rows in MFMA columns, 4 waves x 2 n-tiles,
// bf16 LDS exchange (1 bar_lds/step), 2+2 MFMA split, ring-4 emission
// prefetch, lag-1 pow2 rescale from s[b,0]'s exponent.
__global__ __launch_bounds__(256, 6) void crf_chunk_kernel(
    const float* __restrict__ hs,
    const float* __restrict__ trans,
    const float* __restrict__ start_t,
    const float* __restrict__ end_t,
    float* __restrict__ ws)
{
  __shared__ __align__(16) unsigned short pL[2][ROWS][PSTR];
  __shared__ float sSc[2][ROWS];
  __shared__ float sRed[4][ROWS];

  const int tid = (int)threadIdx.x;
  const int w = tid >> 6;
  const int lane = tid & 63;
  const int b = lane & 15;
  const int kq = lane >> 4;
  const int rb = (int)blockIdx.x & 15;   // batch group
  const int ck = (int)blockIdx.x >> 4;   // time chunk (0..95)
  const int brow = rb * ROWS + b;
  const int s0 = (MEAS * ck) / NC;       // warm-start time
  const int L  = (MEAS * (ck + 1)) / NC - s0;   // measured steps: 10 or 11
  const int NSTEPS = WARM + L;           // 22 or 23 local steps
  const float* __restrict__ eb = hs + (size_t)brow * Tc * Kc + (size_t)s0 * Kc;

  const int jb0 = 32 * w + 4 * kq;
  const int jb1 = jb0 + 16;

  // A-frags: A[m][k] = exp(trans[k][16n+m])  (E^T).
  bf16x8 A[2][4];
#pragma unroll
  for (int np = 0; np < 2; ++np)
#pragma unroll
    for (int tt = 0; tt < 4; ++tt) {
      bf16x8 a;
#pragma unroll
      for (int jj = 0; jj < 8; ++jj) {
        const int kg = 32 * tt + 8 * kq + jj;
        const int rg = 16 * (2 * w + np) + b;
        a[jj] = bf16rne(fast_exp2(trans[(size_t)kg * Kc + rg] * L2E));
      }
      A[np][tt] = a;
    }

  // Emission ring. Slot d holds local row 1+d.
  f32x4 er[4][2];
#pragma unroll
  for (int d = 0; d < 4; ++d) {
    er[d][0] = *(const f32x4*)&eb[(size_t)(1 + d) * Kc + jb0];
    er[d][1] = *(const f32x4*)&eb[(size_t)(1 + d) * Kc + jb1];
  }

  // Init: chunk 0 exact (2^((start+e_0)L2E)); others all-ones (direction warmup).
  if (ck == 0) {
#pragma unroll
    for (int np = 0; np < 2; ++np) {
      const int jb = np ? jb1 : jb0;
      f32x4 sv = *(const f32x4*)&start_t[jb];
      f32x4 e0 = *(const f32x4*)&eb[jb];   // local row 0
      uint32_t d0 = (uint32_t)(uint16_t)bf16rne(fast_exp2((sv.x + e0.x) * L2E)) |
                    ((uint32_t)(uint16_t)bf16rne(fast_exp2((sv.y + e0.y) * L2E)) << 16);
      uint32_t d1 = (uint32_t)(uint16_t)bf16rne(fast_exp2((sv.z + e0.z) * L2E)) |
                    ((uint32_t)(uint16_t)bf16rne(fast_exp2((sv.w + e0.w) * L2E)) << 16);
      *(uint2*)&pL[0][b][jb] = make_uint2(d0, d1);
    }
  } else {
    *(uint2*)&pL[0][b][jb0] = make_uint2(0x3F803F80u, 0x3F803F80u);  // bf16 1.0 x4
    *(uint2*)&pL[0][b][jb1] = make_uint2(0x3F803F80u, 0x3F803F80u);
  }
  bar_lds();
  bf16x8 Bf[4];
#pragma unroll
  for (int tt = 0; tt < 4; ++tt)
    Bf[tt] = *(const bf16x8*)&pL[0][b][32 * tt + 8 * kq];

  float scale = 1.0f;
  int curE0 = 0;
  int Mi = 0;
  f32x4 pf0 = {0, 0, 0, 0}, pf1 = {0, 0, 0, 0};

  auto matvec = [&](f32x4* C) {
#pragma unroll
    for (int np = 0; np < 2; ++np) {
      f32x4 c01 = __builtin_amdgcn_mfma_f32_16x16x32_bf16(
          A[np][1], Bf[1],
          __builtin_amdgcn_mfma_f32_16x16x32_bf16(A[np][0], Bf[0],
                                                  (f32x4){0.f, 0.f, 0.f, 0.f}, 0, 0, 0),
          0, 0, 0);
      f32x4 c23 = __builtin_amdgcn_mfma_f32_16x16x32_bf16(
          A[np][3], Bf[3],
          __builtin_amdgcn_mfma_f32_16x16x32_bf16(A[np][2], Bf[2],
                                                  (f32x4){0.f, 0.f, 0.f, 0.f}, 0, 0, 0),
          0, 0, 0);
      C[np] = c01 + c23;   // two independent 2-chains + one vector add
    }
  };

  auto step = [&](int t, int u) {
    f32x4 C[2];
    matvec(C);
    // scale * 2^(e*L2E) in the MFMA shadow.
    f32x4 se0, se1;
    {
      f32x4 e = er[u][0];
      se0.x = scale * fast_exp2(e.x * L2E); se0.y = scale * fast_exp2(e.y * L2E);
      se0.z = scale * fast_exp2(e.z * L2E); se0.w = scale * fast_exp2(e.w * L2E);
      e = er[u][1];
      se1.x = scale * fast_exp2(e.x * L2E); se1.y = scale * fast_exp2(e.y * L2E);
      se1.z = scale * fast_exp2(e.z * L2E); se1.w = scale * fast_exp2(e.w * L2E);
    }
    Mi += curE0;
    // Ring refill (stays in flight across bar_lds). Local rows, clamp to NSTEPS.
    int rn = t + 4; if (rn > NSTEPS) rn = NSTEPS;
    er[u][0] = *(const f32x4*)&eb[(size_t)rn * Kc + jb0];
    er[u][1] = *(const f32x4*)&eb[(size_t)rn * Kc + jb1];

    const int buf = t & 1;
    {
      f32x4 p;
      p.x = C[0].x * se0.x; p.y = C[0].y * se0.y;
      p.z = C[0].z * se0.z; p.w = C[0].w * se0.w;
      pf0 = p;
      uint32_t d0 = (uint32_t)(uint16_t)bf16rne(p.x) | ((uint32_t)(uint16_t)bf16rne(p.y) << 16);
      uint32_t d1 = (uint32_t)(uint16_t)bf16rne(p.z) | ((uint32_t)(uint16_t)bf16rne(p.w) << 16);
      *(uint2*)&pL[buf][b][jb0] = make_uint2(d0, d1);
      p.x = C[1].x * se1.x; p.y = C[1].y * se1.y;
      p.z = C[1].z * se1.z; p.w = C[1].w * se1.w;
      pf1 = p;
      d0 = (uint32_t)(uint16_t)bf16rne(p.x) | ((uint32_t)(uint16_t)bf16rne(p.y) << 16);
      d1 = (uint32_t)(uint16_t)bf16rne(p.z) | ((uint32_t)(uint16_t)bf16rne(p.w) << 16);
      *(uint2*)&pL[buf][b][jb1] = make_uint2(d0, d1);
    }
    if (w == 0 && kq == 0) sSc[buf][b] = C[0].x;
    bar_lds();
#pragma unroll
    for (int tt = 0; tt < 4; ++tt)
      Bf[tt] = *(const bf16x8*)&pL[buf][b][32 * tt + 8 * kq];
    float s0v = sSc[buf][b];
    uint32_t ex = (__float_as_uint(s0v) >> 23) & 0xffu;
    curE0 = (int)ex - 127;
    scale = __uint_as_float((254u - ex) << 23);
  };

  // A = Mi + log2(sum_j p_hat[j]) per batch row; valid on (w==0, lane<16).
  // weighted=true uses 2^(end_j*L2E) weights (final functional).
  auto measureA = [&](bool weighted) -> float {
    float part;
    if (weighted) {
      f32x4 e0 = *(const f32x4*)&end_t[jb0];
      f32x4 e1 = *(const f32x4*)&end_t[jb1];
      part = pf0.x * fast_exp2(e0.x * L2E) + pf0.y * fast_exp2(e0.y * L2E) +
             pf0.z * fast_exp2(e0.z * L2E) + pf0.w * fast_exp2(e0.w * L2E) +
             pf1.x * fast_exp2(e1.x * L2E) + pf1.y * fast_exp2(e1.y * L2E) +
             pf1.z * fast_exp2(e1.z * L2E) + pf1.w * fast_exp2(e1.w * L2E);
    } else {
      part = pf0.x + pf0.y + pf0.z + pf0.w + pf1.x + pf1.y + pf1.z + pf1.w;
    }
    part += __shfl_xor(part, 16);   // fold kq pairs
    part += __shfl_xor(part, 32);   // all 4 kq groups -> per-wave sum for this b
    if (lane < ROWS) sRed[w][lane] = part;
    bar_lds();
    float Av = 0.f;
    if (w == 0 && lane < ROWS) {
      float S = sRed[0][lane] + sRed[1][lane] + sRed[2][lane] + sRed[3][lane];
      Av = (float)Mi + fast_log2(S);
    }
    return Av;
  };

  // Phase 1: local steps 1..12 — 3 exact quads (u = (t-1)&3, static), then Amid.
  {
    auto quad = [&](int tb) { step(tb, 0); step(tb + 1, 1); step(tb + 2, 2); step(tb + 3, 3); };
    quad(1); quad(5); quad(9);
  }
  const float Amid = measureA(false);

  // Phase 2: local steps 13..12+L (L in {10,11}); u resumes at 0 (13-1 = 12 = 0 mod 4).
  {
    auto quad = [&](int tb) { step(tb, 0); step(tb + 1, 1); step(tb + 2, 2); step(tb + 3, 3); };
    quad(13); quad(17);
    step(21, 0); step(22, 1);
    if (L == 11) step(23, 2);
  }
  const float Aend = measureA(ck == NC - 1);

  if (w == 0 && lane < ROWS)
    ws[(size_t)ck * Bc + brow] = Aend - (ck ? Amid : 0.f);
}

// logZ_b = ln2 * sum_c contrib[c][b]
__global__ __launch_bounds__(256, 1) void crf_combine(
    const float* __restrict__ ws, float* __restrict__ out)
{
  const int b = (int)threadIdx.x;
  float s = 0.f;
#pragma unroll
  for (int cc = 0; cc < NC; ++cc) s += ws[(size_t)cc * Bc + b];
  out[b] = s * LN2;
}

extern "C" void kernel_launch(void* const* d_in, const int* in_sizes, int n_in,
                              void* d_out, int out_size, void* d_ws, size_t ws_size,
                              hipStream_t stream) {
  const float* hs    = (const float*)d_in[0];
  const float* trans = (const float*)d_in[1];
  const float* st    = (const float*)d_in[2];
  const float* en    = (const float*)d_in[3];
  float* ws = (float*)d_ws;   // needs NC*Bc = 24576 floats = 96 KB
  crf_chunk_kernel<<<dim3(NC * Bc / ROWS), dim3(256), 0, stream>>>(hs, trans, st, en, ws);
  crf_combine<<<dim3(1), dim3(Bc), 0, stream>>>(ws, (float*)d_out);
}

// Round 4
// 1062.898 us; speedup vs baseline: 1.0143x; 1.0143x over previous
//
#include <hip/hip_runtime.h>
#include <cstddef>
#include <cstdint>

typedef float f2    __attribute__((ext_vector_type(2)));
typedef float f32x4 __attribute__((ext_vector_type(4)));
typedef short bf16x8 __attribute__((ext_vector_type(8)));

__device__ __forceinline__ float fast_exp2(float x) { return __builtin_amdgcn_exp2f(x); }
__device__ __forceinline__ float fast_log2(float x) { return __builtin_amdgcn_logf(x); }

__device__ __forceinline__ short bf16rne(float x) {
  uint32_t u = __float_as_uint(x);
  u += 0x7fffu + ((u >> 16) & 1u);
  return (short)(u >> 16);
}

// LDS-only barrier: no vmcnt drain, global prefetch stays in flight.
__device__ __forceinline__ void bar_lds() {
  asm volatile("s_waitcnt lgkmcnt(0)\n\ts_barrier" ::: "memory");
}

namespace {
constexpr int Bc = 256, Tc = 1024, Kc = 128;
constexpr int ROWS = 16;
constexpr int NC = 96;          // time chunks -> 1536 blocks = 6 per CU
constexpr int WARM = 12;        // warmup; kappa<=0.29/step -> dir err ~5e-7 << bf16 noise
constexpr int MEAS = 1023 - WARM;  // 1011 measured steps, split via s_c = floor(1011*c/96)
constexpr float L2E = 1.4426950408889634f;
constexpr float LN2 = 0.6931471805599453f;
constexpr int PSTR = 136;
// Workspace: contrib[NC][Bc] floats = 96 KB.
}

// Chunked-telescope CRF forward.
// R3 post-mortem: __launch_bounds__(256,6) forced VGPR 76 -> 40; the engine's
// ~80 live VGPRs (A 32 + er 32 + Bf 16) spilled to scratch (FETCH 2.1 GB,
// WRITE 1.4 GB of pure spill traffic) -> 957us. The GEOMETRY itself worked:
// occupancy 60% (6 blocks/CU resident), absmax 0.0 (WARM=12 numerically fine).
// Fix: revert to (256,3) under which this exact engine compiles to 76 VGPR
// (R2-proven); 76*6 = 456 <= 512 so 6 waves/SIMD occupancy comes naturally
// from the grid, no allocator coercion needed.
// Chunk c: warm-start (ones) at s_c = floor(1011c/96), 12 warmup steps,
// Amid at s_c+12, then L_c = s_{c+1}-s_c in {10,11} measured steps, Aend at
// s_{c+1}+12 (= chunk c+1's Amid point; telescopes). Chunk 0 starts exact
// (2^((start+e_0)L2E)), whole range measured; last chunk ends at 1023 and
// end-weights with 2^(end*L2E).
// logZ = LN2 * [Aend^(0) + sum_{c>=1}(Aend^(c)-Amid^(c))].
// Step engine unchanged: 16 batch rows in MFMA columns, 4 waves x 2 n-tiles,
// bf16 LDS exchange (1 bar_lds/step), 2+2 MFMA split, ring-4 emission
// prefetch, lag-1 pow2 rescale from s[b,0]'s exponent.
__global__ __launch_bounds__(256, 3) void crf_chunk_kernel(
    const float* __restrict__ hs,
    const float* __restrict__ trans,
    const float* __restrict__ start_t,
    const float* __restrict__ end_t,
    float* __restrict__ ws)
{
  __shared__ __align__(16) unsigned short pL[2][ROWS][PSTR];
  __shared__ float sSc[2][ROWS];
  __shared__ float sRed[4][ROWS];

  const int tid = (int)threadIdx.x;
  const int w = tid >> 6;
  const int lane = tid & 63;
  const int b = lane & 15;
  const int kq = lane >> 4;
  const int rb = (int)blockIdx.x & 15;   // batch group
  const int ck = (int)blockIdx.x >> 4;   // time chunk (0..95)
  const int brow = rb * ROWS + b;
  const int s0 = (MEAS * ck) / NC;       // warm-start time
  const int L  = (MEAS * (ck + 1)) / NC - s0;   // measured steps: 10 or 11
  const int NSTEPS = WARM + L;           // 22 or 23 local steps
  const float* __restrict__ eb = hs + (size_t)brow * Tc * Kc + (size_t)s0 * Kc;

  const int jb0 = 32 * w + 4 * kq;
  const int jb1 = jb0 + 16;

  // A-frags: A[m][k] = exp(trans[k][16n+m])  (E^T).
  bf16x8 A[2][4];
#pragma unroll
  for (int np = 0; np < 2; ++np)
#pragma unroll
    for (int tt = 0; tt < 4; ++tt) {
      bf16x8 a;
#pragma unroll
      for (int jj = 0; jj < 8; ++jj) {
        const int kg = 32 * tt + 8 * kq + jj;
        const int rg = 16 * (2 * w + np) + b;
        a[jj] = bf16rne(fast_exp2(trans[(size_t)kg * Kc + rg] * L2E));
      }
      A[np][tt] = a;
    }

  // Emission ring. Slot d holds local row 1+d.
  f32x4 er[4][2];
#pragma unroll
  for (int d = 0; d < 4; ++d) {
    er[d][0] = *(const f32x4*)&eb[(size_t)(1 + d) * Kc + jb0];
    er[d][1] = *(const f32x4*)&eb[(size_t)(1 + d) * Kc + jb1];
  }

  // Init: chunk 0 exact (2^((start+e_0)L2E)); others all-ones (direction warmup).
  if (ck == 0) {
#pragma unroll
    for (int np = 0; np < 2; ++np) {
      const int jb = np ? jb1 : jb0;
      f32x4 sv = *(const f32x4*)&start_t[jb];
      f32x4 e0 = *(const f32x4*)&eb[jb];   // local row 0
      uint32_t d0 = (uint32_t)(uint16_t)bf16rne(fast_exp2((sv.x + e0.x) * L2E)) |
                    ((uint32_t)(uint16_t)bf16rne(fast_exp2((sv.y + e0.y) * L2E)) << 16);
      uint32_t d1 = (uint32_t)(uint16_t)bf16rne(fast_exp2((sv.z + e0.z) * L2E)) |
                    ((uint32_t)(uint16_t)bf16rne(fast_exp2((sv.w + e0.w) * L2E)) << 16);
      *(uint2*)&pL[0][b][jb] = make_uint2(d0, d1);
    }
  } else {
    *(uint2*)&pL[0][b][jb0] = make_uint2(0x3F803F80u, 0x3F803F80u);  // bf16 1.0 x4
    *(uint2*)&pL[0][b][jb1] = make_uint2(0x3F803F80u, 0x3F803F80u);
  }
  bar_lds();
  bf16x8 Bf[4];
#pragma unroll
  for (int tt = 0; tt < 4; ++tt)
    Bf[tt] = *(const bf16x8*)&pL[0][b][32 * tt + 8 * kq];

  float scale = 1.0f;
  int curE0 = 0;
  int Mi = 0;
  f32x4 pf0 = {0, 0, 0, 0}, pf1 = {0, 0, 0, 0};

  auto matvec = [&](f32x4* C) {
#pragma unroll
    for (int np = 0; np < 2; ++np) {
      f32x4 c01 = __builtin_amdgcn_mfma_f32_16x16x32_bf16(
          A[np][1], Bf[1],
          __builtin_amdgcn_mfma_f32_16x16x32_bf16(A[np][0], Bf[0],
                                                  (f32x4){0.f, 0.f, 0.f, 0.f}, 0, 0, 0),
          0, 0, 0);
      f32x4 c23 = __builtin_amdgcn_mfma_f32_16x16x32_bf16(
          A[np][3], Bf[3],
          __builtin_amdgcn_mfma_f32_16x16x32_bf16(A[np][2], Bf[2],
                                                  (f32x4){0.f, 0.f, 0.f, 0.f}, 0, 0, 0),
          0, 0, 0);
      C[np] = c01 + c23;   // two independent 2-chains + one vector add
    }
  };

  auto step = [&](int t, int u) {
    f32x4 C[2];
    matvec(C);
    // scale * 2^(e*L2E) in the MFMA shadow.
    f32x4 se0, se1;
    {
      f32x4 e = er[u][0];
      se0.x = scale * fast_exp2(e.x * L2E); se0.y = scale * fast_exp2(e.y * L2E);
      se0.z = scale * fast_exp2(e.z * L2E); se0.w = scale * fast_exp2(e.w * L2E);
      e = er[u][1];
      se1.x = scale * fast_exp2(e.x * L2E); se1.y = scale * fast_exp2(e.y * L2E);
      se1.z = scale * fast_exp2(e.z * L2E); se1.w = scale * fast_exp2(e.w * L2E);
    }
    Mi += curE0;
    // Ring refill (stays in flight across bar_lds). Local rows, clamp to NSTEPS.
    int rn = t + 4; if (rn > NSTEPS) rn = NSTEPS;
    er[u][0] = *(const f32x4*)&eb[(size_t)rn * Kc + jb0];
    er[u][1] = *(const f32x4*)&eb[(size_t)rn * Kc + jb1];

    const int buf = t & 1;
    {
      f32x4 p;
      p.x = C[0].x * se0.x; p.y = C[0].y * se0.y;
      p.z = C[0].z * se0.z; p.w = C[0].w * se0.w;
      pf0 = p;
      uint32_t d0 = (uint32_t)(uint16_t)bf16rne(p.x) | ((uint32_t)(uint16_t)bf16rne(p.y) << 16);
      uint32_t d1 = (uint32_t)(uint16_t)bf16rne(p.z) | ((uint32_t)(uint16_t)bf16rne(p.w) << 16);
      *(uint2*)&pL[buf][b][jb0] = make_uint2(d0, d1);
      p.x = C[1].x * se1.x; p.y = C[1].y * se1.y;
      p.z = C[1].z * se1.z; p.w = C[1].w * se1.w;
      pf1 = p;
      d0 = (uint32_t)(uint16_t)bf16rne(p.x) | ((uint32_t)(uint16_t)bf16rne(p.y) << 16);
      d1 = (uint32_t)(uint16_t)bf16rne(p.z) | ((uint32_t)(uint16_t)bf16rne(p.w) << 16);
      *(uint2*)&pL[buf][b][jb1] = make_uint2(d0, d1);
    }
    if (w == 0 && kq == 0) sSc[buf][b] = C[0].x;
    bar_lds();
#pragma unroll
    for (int tt = 0; tt < 4; ++tt)
      Bf[tt] = *(const bf16x8*)&pL[buf][b][32 * tt + 8 * kq];
    float s0v = sSc[buf][b];
    uint32_t ex = (__float_as_uint(s0v) >> 23) & 0xffu;
    curE0 = (int)ex - 127;
    scale = __uint_as_float((254u - ex) << 23);
  };

  // A = Mi + log2(sum_j p_hat[j]) per batch row; valid on (w==0, lane<16).
  // weighted=true uses 2^(end_j*L2E) weights (final functional).
  auto measureA = [&](bool weighted) -> float {
    float part;
    if (weighted) {
      f32x4 e0 = *(const f32x4*)&end_t[jb0];
      f32x4 e1 = *(const f32x4*)&end_t[jb1];
      part = pf0.x * fast_exp2(e0.x * L2E) + pf0.y * fast_exp2(e0.y * L2E) +
             pf0.z * fast_exp2(e0.z * L2E) + pf0.w * fast_exp2(e0.w * L2E) +
             pf1.x * fast_exp2(e1.x * L2E) + pf1.y * fast_exp2(e1.y * L2E) +
             pf1.z * fast_exp2(e1.z * L2E) + pf1.w * fast_exp2(e1.w * L2E);
    } else {
      part = pf0.x + pf0.y + pf0.z + pf0.w + pf1.x + pf1.y + pf1.z + pf1.w;
    }
    part += __shfl_xor(part, 16);   // fold kq pairs
    part += __shfl_xor(part, 32);   // all 4 kq groups -> per-wave sum for this b
    if (lane < ROWS) sRed[w][lane] = part;
    bar_lds();
    float Av = 0.f;
    if (w == 0 && lane < ROWS) {
      float S = sRed[0][lane] + sRed[1][lane] + sRed[2][lane] + sRed[3][lane];
      Av = (float)Mi + fast_log2(S);
    }
    return Av;
  };

  // Phase 1: local steps 1..12 — 3 exact quads (u = (t-1)&3, static), then Amid.
  {
    auto quad = [&](int tb) { step(tb, 0); step(tb + 1, 1); step(tb + 2, 2); step(tb + 3, 3); };
    quad(1); quad(5); quad(9);
  }
  const float Amid = measureA(false);

  // Phase 2: local steps 13..12+L (L in {10,11}); u resumes at 0 (13-1 = 12 = 0 mod 4).
  {
    auto quad = [&](int tb) { step(tb, 0); step(tb + 1, 1); step(tb + 2, 2); step(tb + 3, 3); };
    quad(13); quad(17);
    step(21, 0); step(22, 1);
    if (L == 11) step(23, 2);
  }
  const float Aend = measureA(ck == NC - 1);

  if (w == 0 && lane < ROWS)
    ws[(size_t)ck * Bc + brow] = Aend - (ck ? Amid : 0.f);
}

// logZ_b = ln2 * sum_c contrib[c][b]
__global__ __launch_bounds__(256, 1) void crf_combine(
    const float* __restrict__ ws, float* __restrict__ out)
{
  const int b = (int)threadIdx.x;
  float s = 0.f;
#pragma unroll
  for (int cc = 0; cc < NC; ++cc) s += ws[(size_t)cc * Bc + b];
  out[b] = s * LN2;
}

extern "C" void kernel_launch(void* const* d_in, const int* in_sizes, int n_in,
                              void* d_out, int out_size, void* d_ws, size_t ws_size,
                              hipStream_t stream) {
  const float* hs    = (const float*)d_in[0];
  const float* trans = (const float*)d_in[1];
  const float* st    = (const float*)d_in[2];
  const float* en    = (const float*)d_in[3];
  float* ws = (float*)d_ws;   // needs NC*Bc = 24576 floats = 96 KB
  crf_chunk_kernel<<<dim3(NC * Bc / ROWS), dim3(256), 0, stream>>>(hs, trans, st, en, ws);
  crf_combine<<<dim3(1), dim3(Bc), 0, stream>>>(ws, (float*)d_out);
}

// Round 5
// 208.971 us; speedup vs baseline: 5.1589x; 5.0864x over previous
//
#include <hip/hip_runtime.h>
#include <cstddef>
#include <cstdint>

typedef float f2    __attribute__((ext_vector_type(2)));
typedef float f32x4 __attribute__((ext_vector_type(4)));
typedef short bf16x8 __attribute__((ext_vector_type(8)));

__device__ __forceinline__ float fast_exp2(float x) { return __builtin_amdgcn_exp2f(x); }
__device__ __forceinline__ float fast_log2(float x) { return __builtin_amdgcn_logf(x); }

__device__ __forceinline__ short bf16rne(float x) {
  uint32_t u = __float_as_uint(x);
  u += 0x7fffu + ((u >> 16) & 1u);
  return (short)(u >> 16);
}

// LDS-only barrier: no vmcnt drain, global prefetch stays in flight.
__device__ __forceinline__ void bar_lds() {
  asm volatile("s_waitcnt lgkmcnt(0)\n\ts_barrier" ::: "memory");
}

namespace {
constexpr int Bc = 256, Tc = 1024, Kc = 128;
constexpr int ROWS = 16;
constexpr int NC = 96;          // time chunks -> 1536 blocks = 6 per CU
constexpr int WARM = 12;        // warmup; kappa<=0.29/step -> dir err ~5e-7 << bf16 noise
constexpr int MEAS = 1023 - WARM;  // 1011 measured steps, s_c = floor(1011*c/96)
constexpr float L2E = 1.4426950408889634f;
constexpr float LN2 = 0.6931471805599453f;
constexpr int PSTR = 136;
// Workspace: contrib[NC][Bc] floats = 96 KB.
}

// Chunked-telescope CRF forward.
// R4 post-mortem: the R3 quad->step nested-lambda restructure made the
// compiler OUTLINE step(); its [&]-captured state + runtime-indexed er[u]
// went to scratch (rule #20): WRITE_SIZE 1.41 GB vs 96 KB real output,
// FETCH 1.96 GB, ~945us — identical in R3 and R4, so launch_bounds was NOT
// the cause. R2's clean codegen (76 VGPR, zero scratch) came from fully
// static step expansion. Fix: STEP(T,U) is now a preprocessor MACRO with
// literal T/U at every expansion — er[U]/pL[T&1]/A/Bf all statically
// indexed, no inliner discretion. Geometry kept from R3: NC=96 -> 1536
// blocks = 6/CU (proven co-resident in R3: 60% occupancy), WARM=12.
// Chunk c: warm-start (ones) at s_c = floor(1011c/96), 12 warmup steps,
// Amid at s_c+12, then L_c = s_{c+1}-s_c in {10,11} measured steps, Aend
// at s_{c+1}+12 (= chunk c+1's Amid; telescopes). Chunk 0 exact-start
// (2^((start+e_0)L2E)), whole range measured; chunk 95 ends at t=1023 and
// end-weights with 2^(end*L2E).
// logZ = LN2 * [Aend^(0) + sum_{c>=1}(Aend^(c)-Amid^(c))].
// Step engine (R2-verified): 16 batch rows in MFMA columns, 4 waves x 2
// n-tiles, bf16 LDS exchange (1 bar_lds/step), 2+2 MFMA split, ring-4
// emission prefetch, lag-1 pow2 rescale from s[b,0]'s exponent.
__global__ __launch_bounds__(256, 3) void crf_chunk_kernel(
    const float* __restrict__ hs,
    const float* __restrict__ trans,
    const float* __restrict__ start_t,
    const float* __restrict__ end_t,
    float* __restrict__ ws)
{
  __shared__ __align__(16) unsigned short pL[2][ROWS][PSTR];
  __shared__ float sSc[2][ROWS];
  __shared__ float sRed[4][ROWS];

  const int tid = (int)threadIdx.x;
  const int w = tid >> 6;
  const int lane = tid & 63;
  const int b = lane & 15;
  const int kq = lane >> 4;
  const int rb = (int)blockIdx.x & 15;   // batch group
  const int ck = (int)blockIdx.x >> 4;   // time chunk (0..95)
  const int brow = rb * ROWS + b;
  const int s0 = (MEAS * ck) / NC;       // warm-start time
  const int L  = (MEAS * (ck + 1)) / NC - s0;   // measured steps: 10 or 11
  const int NSTEPS = WARM + L;           // 22 or 23 local steps
  const float* __restrict__ eb = hs + (size_t)brow * Tc * Kc + (size_t)s0 * Kc;

  const int jb0 = 32 * w + 4 * kq;
  const int jb1 = jb0 + 16;

  // A-frags: A[m][k] = exp(trans[k][16n+m])  (E^T).
  bf16x8 A[2][4];
#pragma unroll
  for (int np = 0; np < 2; ++np)
#pragma unroll
    for (int tt = 0; tt < 4; ++tt) {
      bf16x8 a;
#pragma unroll
      for (int jj = 0; jj < 8; ++jj) {
        const int kg = 32 * tt + 8 * kq + jj;
        const int rg = 16 * (2 * w + np) + b;
        a[jj] = bf16rne(fast_exp2(trans[(size_t)kg * Kc + rg] * L2E));
      }
      A[np][tt] = a;
    }

  // Emission ring. Slot d holds local row 1+d.
  f32x4 er[4][2];
#pragma unroll
  for (int d = 0; d < 4; ++d) {
    er[d][0] = *(const f32x4*)&eb[(size_t)(1 + d) * Kc + jb0];
    er[d][1] = *(const f32x4*)&eb[(size_t)(1 + d) * Kc + jb1];
  }

  // Init: chunk 0 exact (2^((start+e_0)L2E)); others all-ones (direction warmup).
  if (ck == 0) {
#pragma unroll
    for (int np = 0; np < 2; ++np) {
      const int jb = np ? jb1 : jb0;
      f32x4 sv = *(const f32x4*)&start_t[jb];
      f32x4 e0 = *(const f32x4*)&eb[jb];   // local row 0
      uint32_t d0 = (uint32_t)(uint16_t)bf16rne(fast_exp2((sv.x + e0.x) * L2E)) |
                    ((uint32_t)(uint16_t)bf16rne(fast_exp2((sv.y + e0.y) * L2E)) << 16);
      uint32_t d1 = (uint32_t)(uint16_t)bf16rne(fast_exp2((sv.z + e0.z) * L2E)) |
                    ((uint32_t)(uint16_t)bf16rne(fast_exp2((sv.w + e0.w) * L2E)) << 16);
      *(uint2*)&pL[0][b][jb] = make_uint2(d0, d1);
    }
  } else {
    *(uint2*)&pL[0][b][jb0] = make_uint2(0x3F803F80u, 0x3F803F80u);  // bf16 1.0 x4
    *(uint2*)&pL[0][b][jb1] = make_uint2(0x3F803F80u, 0x3F803F80u);
  }
  bar_lds();
  bf16x8 Bf[4];
#pragma unroll
  for (int tt = 0; tt < 4; ++tt)
    Bf[tt] = *(const bf16x8*)&pL[0][b][32 * tt + 8 * kq];

  float scale = 1.0f;
  int curE0 = 0;
  int Mi = 0;
  f32x4 pf0 = {0, 0, 0, 0}, pf1 = {0, 0, 0, 0};

// One CRF step, fully macro-expanded: T = local step index (literal),
// U = ring slot (literal, = (T-1)&3). All array indices compile-time.
#define STEP(T, U) do {                                                         \
    const f32x4 z4 = {0.f, 0.f, 0.f, 0.f};                                      \
    f32x4 c01 = __builtin_amdgcn_mfma_f32_16x16x32_bf16(A[0][1], Bf[1],         \
        __builtin_amdgcn_mfma_f32_16x16x32_bf16(A[0][0], Bf[0], z4, 0, 0, 0),   \
        0, 0, 0);                                                               \
    f32x4 c23 = __builtin_amdgcn_mfma_f32_16x16x32_bf16(A[0][3], Bf[3],         \
        __builtin_amdgcn_mfma_f32_16x16x32_bf16(A[0][2], Bf[2], z4, 0, 0, 0),   \
        0, 0, 0);                                                               \
    const f32x4 C0 = c01 + c23;                                                 \
    c01 = __builtin_amdgcn_mfma_f32_16x16x32_bf16(A[1][1], Bf[1],               \
        __builtin_amdgcn_mfma_f32_16x16x32_bf16(A[1][0], Bf[0], z4, 0, 0, 0),   \
        0, 0, 0);                                                               \
    c23 = __builtin_amdgcn_mfma_f32_16x16x32_bf16(A[1][3], Bf[3],               \
        __builtin_amdgcn_mfma_f32_16x16x32_bf16(A[1][2], Bf[2], z4, 0, 0, 0),   \
        0, 0, 0);                                                               \
    const f32x4 C1 = c01 + c23;                                                 \
    f32x4 se0, se1;                                                             \
    {                                                                           \
      f32x4 e = er[U][0];                                                       \
      se0.x = scale * fast_exp2(e.x * L2E); se0.y = scale * fast_exp2(e.y * L2E); \
      se0.z = scale * fast_exp2(e.z * L2E); se0.w = scale * fast_exp2(e.w * L2E); \
      e = er[U][1];                                                             \
      se1.x = scale * fast_exp2(e.x * L2E); se1.y = scale * fast_exp2(e.y * L2E); \
      se1.z = scale * fast_exp2(e.z * L2E); se1.w = scale * fast_exp2(e.w * L2E); \
    }                                                                           \
    Mi += curE0;                                                                \
    {                                                                           \
      int rn = (T) + 4; if (rn > NSTEPS) rn = NSTEPS;                           \
      er[U][0] = *(const f32x4*)&eb[(size_t)rn * Kc + jb0];                     \
      er[U][1] = *(const f32x4*)&eb[(size_t)rn * Kc + jb1];                     \
    }                                                                           \
    {                                                                           \
      f32x4 p;                                                                  \
      p.x = C0.x * se0.x; p.y = C0.y * se0.y;                                   \
      p.z = C0.z * se0.z; p.w = C0.w * se0.w;                                   \
      pf0 = p;                                                                  \
      uint32_t d0 = (uint32_t)(uint16_t)bf16rne(p.x) | ((uint32_t)(uint16_t)bf16rne(p.y) << 16); \
      uint32_t d1 = (uint32_t)(uint16_t)bf16rne(p.z) | ((uint32_t)(uint16_t)bf16rne(p.w) << 16); \
      *(uint2*)&pL[(T) & 1][b][jb0] = make_uint2(d0, d1);                       \
      p.x = C1.x * se1.x; p.y = C1.y * se1.y;                                   \
      p.z = C1.z * se1.z; p.w = C1.w * se1.w;                                   \
      pf1 = p;                                                                  \
      d0 = (uint32_t)(uint16_t)bf16rne(p.x) | ((uint32_t)(uint16_t)bf16rne(p.y) << 16); \
      d1 = (uint32_t)(uint16_t)bf16rne(p.z) | ((uint32_t)(uint16_t)bf16rne(p.w) << 16); \
      *(uint2*)&pL[(T) & 1][b][jb1] = make_uint2(d0, d1);                       \
    }                                                                           \
    if (w == 0 && kq == 0) sSc[(T) & 1][b] = C0.x;                              \
    bar_lds();                                                                  \
    Bf[0] = *(const bf16x8*)&pL[(T) & 1][b][8 * kq];                            \
    Bf[1] = *(const bf16x8*)&pL[(T) & 1][b][32 + 8 * kq];                       \
    Bf[2] = *(const bf16x8*)&pL[(T) & 1][b][64 + 8 * kq];                       \
    Bf[3] = *(const bf16x8*)&pL[(T) & 1][b][96 + 8 * kq];                       \
    {                                                                           \
      float s0v = sSc[(T) & 1][b];                                              \
      uint32_t ex = (__float_as_uint(s0v) >> 23) & 0xffu;                       \
      curE0 = (int)ex - 127;                                                    \
      scale = __uint_as_float((254u - ex) << 23);                               \
    }                                                                           \
  } while (0)

  // A = Mi + log2(sum_j p_hat[j]) per batch row; valid on (w==0, lane<16).
  // weighted=true uses 2^(end_j*L2E) weights (final functional).
  auto measureA = [&](bool weighted) -> float {
    float part;
    if (weighted) {
      f32x4 e0 = *(const f32x4*)&end_t[jb0];
      f32x4 e1 = *(const f32x4*)&end_t[jb1];
      part = pf0.x * fast_exp2(e0.x * L2E) + pf0.y * fast_exp2(e0.y * L2E) +
             pf0.z * fast_exp2(e0.z * L2E) + pf0.w * fast_exp2(e0.w * L2E) +
             pf1.x * fast_exp2(e1.x * L2E) + pf1.y * fast_exp2(e1.y * L2E) +
             pf1.z * fast_exp2(e1.z * L2E) + pf1.w * fast_exp2(e1.w * L2E);
    } else {
      part = pf0.x + pf0.y + pf0.z + pf0.w + pf1.x + pf1.y + pf1.z + pf1.w;
    }
    part += __shfl_xor(part, 16);   // fold kq pairs
    part += __shfl_xor(part, 32);   // all 4 kq groups -> per-wave sum for this b
    if (lane < ROWS) sRed[w][lane] = part;
    bar_lds();
    float Av = 0.f;
    if (w == 0 && lane < ROWS) {
      float S = sRed[0][lane] + sRed[1][lane] + sRed[2][lane] + sRed[3][lane];
      Av = (float)Mi + fast_log2(S);
    }
    return Av;
  };

  // Phase 1: local steps 1..12 (warmup; measured for ck==0), then Amid.
  STEP(1, 0);  STEP(2, 1);  STEP(3, 2);  STEP(4, 3);
  STEP(5, 0);  STEP(6, 1);  STEP(7, 2);  STEP(8, 3);
  STEP(9, 0);  STEP(10, 1); STEP(11, 2); STEP(12, 3);
  const float Amid = measureA(false);

  // Phase 2: local steps 13..12+L (L in {10,11}); ring phase resumes at 0.
  STEP(13, 0); STEP(14, 1); STEP(15, 2); STEP(16, 3);
  STEP(17, 0); STEP(18, 1); STEP(19, 2); STEP(20, 3);
  STEP(21, 0); STEP(22, 1);
  if (L == 11) { STEP(23, 2); }
  const float Aend = measureA(ck == NC - 1);

#undef STEP

  if (w == 0 && lane < ROWS)
    ws[(size_t)ck * Bc + brow] = Aend - (ck ? Amid : 0.f);
}

// logZ_b = ln2 * sum_c contrib[c][b]
__global__ __launch_bounds__(256, 1) void crf_combine(
    const float* __restrict__ ws, float* __restrict__ out)
{
  const int b = (int)threadIdx.x;
  float s = 0.f;
#pragma unroll
  for (int cc = 0; cc < NC; ++cc) s += ws[(size_t)cc * Bc + b];
  out[b] = s * LN2;
}

extern "C" void kernel_launch(void* const* d_in, const int* in_sizes, int n_in,
                              void* d_out, int out_size, void* d_ws, size_t ws_size,
                              hipStream_t stream) {
  const float* hs    = (const float*)d_in[0];
  const float* trans = (const float*)d_in[1];
  const float* st    = (const float*)d_in[2];
  const float* en    = (const float*)d_in[3];
  float* ws = (float*)d_ws;   // needs NC*Bc = 24576 floats = 96 KB
  crf_chunk_kernel<<<dim3(NC * Bc / ROWS), dim3(256), 0, stream>>>(hs, trans, st, en, ws);
  crf_combine<<<dim3(1), dim3(Bc), 0, stream>>>(ws, (float*)d_out);
}